// Round 1
// baseline (2525.310 us; speedup 1.0000x reference)
//
#include <hip/hip_runtime.h>
#include <math.h>

#define N 4096
#define D 2048
#define H 512
#define C 200
#define NR 8192  // 2N

typedef unsigned long long u64;
typedef unsigned int u32;

__device__ __forceinline__ float sigm(float z) { return 1.0f / (1.0f + expf(-z)); }
__device__ __forceinline__ float bf2f(unsigned short u) { return __uint_as_float(((u32)u) << 16); }
__device__ __forceinline__ unsigned short f2bf(float x) {
  u32 u = __float_as_uint(x);
  u32 r = (u + 0x7fffu + ((u >> 16) & 1u)) >> 16;  // RNE
  return (unsigned short)r;
}

#define FMA16(av, bv) do { \
  acc[0][0] = fmaf(av.x, bv.x, acc[0][0]); \
  acc[0][1] = fmaf(av.x, bv.y, acc[0][1]); \
  acc[0][2] = fmaf(av.x, bv.z, acc[0][2]); \
  acc[0][3] = fmaf(av.x, bv.w, acc[0][3]); \
  acc[1][0] = fmaf(av.y, bv.x, acc[1][0]); \
  acc[1][1] = fmaf(av.y, bv.y, acc[1][1]); \
  acc[1][2] = fmaf(av.y, bv.z, acc[1][2]); \
  acc[1][3] = fmaf(av.y, bv.w, acc[1][3]); \
  acc[2][0] = fmaf(av.z, bv.x, acc[2][0]); \
  acc[2][1] = fmaf(av.z, bv.y, acc[2][1]); \
  acc[2][2] = fmaf(av.z, bv.z, acc[2][2]); \
  acc[2][3] = fmaf(av.z, bv.w, acc[2][3]); \
  acc[3][0] = fmaf(av.w, bv.x, acc[3][0]); \
  acc[3][1] = fmaf(av.w, bv.y, acc[3][1]); \
  acc[3][2] = fmaf(av.w, bv.z, acc[3][2]); \
  acc[3][3] = fmaf(av.w, bv.w, acc[3][3]); \
} while (0)

// ---------------- K1: row sum of squares + init argmin buffers ----------------
__global__ __launch_bounds__(64) void k1_sumsq(const float* __restrict__ feats,
                                               float* __restrict__ sq,
                                               u64* __restrict__ bi, u64* __restrict__ be) {
  const int row = blockIdx.x;
  const float4* fp = (const float4*)(feats + (size_t)row * D);
  float s = 0.0f;
  for (int i = threadIdx.x; i < D / 4; i += 64) {
    float4 v = fp[i];
    s += v.x * v.x + v.y * v.y + v.z * v.z + v.w * v.w;
  }
  for (int off = 32; off > 0; off >>= 1) s += __shfl_down(s, off);
  if (threadIdx.x == 0) { sq[row] = s; bi[row] = ~0ull; be[row] = ~0ull; }
}

// ---------------- K2: feats @ feats^T tile + fused masked argmin ----------------
#define TS 64
#define BK 32
__global__ __launch_bounds__(256) void k2_dist(const float* __restrict__ feats,
                                               const int* __restrict__ tgt,
                                               const float* __restrict__ sq,
                                               u64* __restrict__ bi, u64* __restrict__ be) {
  __shared__ float As[BK][TS];
  __shared__ float Bs[BK][TS];
  __shared__ int ti[TS], tj[TS];
  __shared__ float sqi[TS], sqj[TS];
  __shared__ u64 lmin[2][TS];
  const int tid = threadIdx.x;
  const int j0 = blockIdx.x * TS;
  const int i0 = blockIdx.y * TS;

  if (tid < TS) { ti[tid] = tgt[i0 + tid]; sqi[tid] = sq[i0 + tid]; }
  else if (tid < 2 * TS) { const int t = tid - TS; tj[t] = tgt[j0 + t]; sqj[t] = sq[j0 + t]; }
  if (tid < 2 * TS) lmin[tid >> 6][tid & 63] = ~0ull;

  float acc[4][4] = {};
  const int lr = tid >> 3;
  const int lk = (tid & 7) << 2;
  const int tr = (tid >> 4) << 2;
  const int tc = (tid & 15) << 2;

  for (int k0 = 0; k0 < D; k0 += BK) {
    __syncthreads();
#pragma unroll
    for (int rep = 0; rep < 2; ++rep) {
      const int row = lr + rep * 32;
      float4 av = *(const float4*)(feats + (size_t)(i0 + row) * D + k0 + lk);
      float4 bv = *(const float4*)(feats + (size_t)(j0 + row) * D + k0 + lk);
      As[lk + 0][row] = av.x; As[lk + 1][row] = av.y; As[lk + 2][row] = av.z; As[lk + 3][row] = av.w;
      Bs[lk + 0][row] = bv.x; Bs[lk + 1][row] = bv.y; Bs[lk + 2][row] = bv.z; Bs[lk + 3][row] = bv.w;
    }
    __syncthreads();
#pragma unroll
    for (int kk = 0; kk < BK; ++kk) {
      float4 av = *(const float4*)&As[kk][tr];
      float4 bv = *(const float4*)&Bs[kk][tc];
      FMA16(av, bv);
    }
  }

#pragma unroll
  for (int ii = 0; ii < 4; ++ii) {
    const int i = i0 + tr + ii;
    const int ci = ti[tr + ii];
    const float si = sqi[tr + ii];
#pragma unroll
    for (int jj = 0; jj < 4; ++jj) {
      const int j = j0 + tc + jj;
      const float d2 = si + sqj[tc + jj] - 2.0f * acc[ii][jj];
      const u64 key = ((u64)__float_as_uint(d2) << 32) | (u32)j;
      if (ci == tj[tc + jj]) {
        if (i != j) atomicMin(&lmin[0][tr + ii], key);
      } else {
        atomicMin(&lmin[1][tr + ii], key);
      }
    }
  }
  __syncthreads();
  if (tid < TS) {
    const u64 v = lmin[0][tid];
    if (v != ~0ull) atomicMin(&bi[i0 + tid], v);
  } else if (tid < 2 * TS) {
    const u64 v = lmin[1][tid - TS];
    if (v != ~0ull) atomicMin(&be[i0 + tid - TS], v);
  }
}

// ---------------- K3: extract pair indices + write label outputs ----------------
__global__ __launch_bounds__(256) void k3_prep(const int* __restrict__ tgt,
                                               const u64* __restrict__ bi,
                                               const u64* __restrict__ be,
                                               int* __restrict__ iy,
                                               float* __restrict__ lab1,
                                               float* __restrict__ lab2) {
  const int r = blockIdx.x * 256 + threadIdx.x;
  if (r >= NR) return;
  if (r < N) {
    iy[r] = (int)(bi[r] & 0xffffffffull);
    const float t = (float)tgt[r];
    lab1[r] = t; lab2[r] = t;
  } else {
    const int s = r - N;
    const int j = (int)(be[s] & 0xffffffffull);
    iy[r] = j;
    lab1[r] = (float)tgt[s];
    lab2[r] = (float)tgt[j];
  }
}

// ---------------- K4: h = [x,y] @ w1 + b1 (A rows gathered from feats) ----------------
__global__ __launch_bounds__(256) void k4_h(const float* __restrict__ feats,
                                            const float* __restrict__ w1,
                                            const float* __restrict__ b1,
                                            const int* __restrict__ iy,
                                            float* __restrict__ hbuf) {
  __shared__ float As[BK][TS];
  __shared__ float Bs[BK][TS];
  __shared__ int rowy[TS];
  const int tid = threadIdx.x;
  const int n0 = blockIdx.x * TS;
  const int r0 = blockIdx.y * TS;
  if (tid < TS) rowy[tid] = iy[r0 + tid];

  float acc[4][4] = {};
  const int lr = tid >> 3;
  const int lk = (tid & 7) << 2;
  const int tr = (tid >> 4) << 2;
  const int tc = (tid & 15) << 2;

  for (int k0 = 0; k0 < 2 * D; k0 += BK) {
    __syncthreads();
    const int kb = (k0 < D) ? k0 : k0 - D;
    const bool xh = (k0 < D);
#pragma unroll
    for (int rep = 0; rep < 2; ++rep) {
      const int row = lr + rep * 32;
      const int gr = xh ? ((r0 + row) & (N - 1)) : rowy[row];
      float4 av = *(const float4*)(feats + (size_t)gr * D + kb + lk);
      As[lk + 0][row] = av.x; As[lk + 1][row] = av.y; As[lk + 2][row] = av.z; As[lk + 3][row] = av.w;
    }
#pragma unroll
    for (int rep = 0; rep < 2; ++rep) {
      const int idx = rep * 256 + tid;
      const int kk = idx >> 4;
      const int c4 = (idx & 15) << 2;
      *(float4*)&Bs[kk][c4] = *(const float4*)(w1 + (size_t)(k0 + kk) * H + n0 + c4);
    }
    __syncthreads();
#pragma unroll
    for (int kk = 0; kk < BK; ++kk) {
      float4 av = *(const float4*)&As[kk][tr];
      float4 bv = *(const float4*)&Bs[kk][tc];
      FMA16(av, bv);
    }
  }
#pragma unroll
  for (int ii = 0; ii < 4; ++ii) {
    const int r = r0 + tr + ii;
    float4 o;
    o.x = acc[ii][0] + b1[n0 + tc + 0];
    o.y = acc[ii][1] + b1[n0 + tc + 1];
    o.z = acc[ii][2] + b1[n0 + tc + 2];
    o.w = acc[ii][3] + b1[n0 + tc + 3];
    *(float4*)(hbuf + (size_t)r * H + n0 + tc) = o;
  }
}

// ---------------- K5: m = h @ w2 + b2 (stored bf16) ----------------
__global__ __launch_bounds__(256) void k5_m(const float* __restrict__ hbuf,
                                            const float* __restrict__ w2,
                                            const float* __restrict__ b2,
                                            unsigned short* __restrict__ mbuf) {
  __shared__ float As[BK][TS];
  __shared__ float Bs[BK][TS];
  const int tid = threadIdx.x;
  const int n0 = blockIdx.x * TS;
  const int r0 = blockIdx.y * TS;
  float acc[4][4] = {};
  const int lr = tid >> 3;
  const int lk = (tid & 7) << 2;
  const int tr = (tid >> 4) << 2;
  const int tc = (tid & 15) << 2;

  for (int k0 = 0; k0 < H; k0 += BK) {
    __syncthreads();
#pragma unroll
    for (int rep = 0; rep < 2; ++rep) {
      const int row = lr + rep * 32;
      float4 av = *(const float4*)(hbuf + (size_t)(r0 + row) * H + k0 + lk);
      As[lk + 0][row] = av.x; As[lk + 1][row] = av.y; As[lk + 2][row] = av.z; As[lk + 3][row] = av.w;
    }
#pragma unroll
    for (int rep = 0; rep < 2; ++rep) {
      const int idx = rep * 256 + tid;
      const int kk = idx >> 4;
      const int c4 = (idx & 15) << 2;
      *(float4*)&Bs[kk][c4] = *(const float4*)(w2 + (size_t)(k0 + kk) * D + n0 + c4);
    }
    __syncthreads();
#pragma unroll
    for (int kk = 0; kk < BK; ++kk) {
      float4 av = *(const float4*)&As[kk][tr];
      float4 bv = *(const float4*)&Bs[kk][tc];
      FMA16(av, bv);
    }
  }
#pragma unroll
  for (int ii = 0; ii < 4; ++ii) {
    const int r = r0 + tr + ii;
    ushort4 o;
    o.x = f2bf(acc[ii][0] + b2[n0 + tc + 0]);
    o.y = f2bf(acc[ii][1] + b2[n0 + tc + 1]);
    o.z = f2bf(acc[ii][2] + b2[n0 + tc + 2]);
    o.w = f2bf(acc[ii][3] + b2[n0 + tc + 3]);
    *(ushort4*)(mbuf + (size_t)r * D + n0 + tc) = o;
  }
}

// ---------------- K6: fused gates + 4 logit GEMMs + sigmoid ----------------
#define KC 1024
__global__ __launch_bounds__(256) void k6_logits(const float* __restrict__ feats,
                                                 const unsigned short* __restrict__ mbuf,
                                                 const int* __restrict__ iy,
                                                 const float* __restrict__ wfc,
                                                 const float* __restrict__ bfc,
                                                 float* __restrict__ out) {
  __shared__ float Al[4][KC][4];  // 64 KB: [row][k][variant]
  const int tid = threadIdx.x;
  const int wid = tid >> 6;   // wave id -> row within block
  const int lane = tid & 63;
  const int r0 = blockIdx.x * 4;
  float acc[4][4] = {};  // [variant][col-sub]

  for (int k0 = 0; k0 < D; k0 += KC) {
    __syncthreads();
#pragma unroll
    for (int rep = 0; rep < 16; ++rep) {
      const int idx = rep * 256 + tid;
      const int rr = idx >> 10;
      const int kk = idx & (KC - 1);
      const int rg = r0 + rr;
      const float x = feats[(size_t)(rg & (N - 1)) * D + k0 + kk];
      const float y = feats[(size_t)iy[rg] * D + k0 + kk];
      const float m = bf2f(mbuf[(size_t)rg * D + k0 + kk]);
      const float gx = sigm(m * x);
      const float gy = sigm(m * y);
      float4 a;
      a.x = x * (1.0f + gx);  // logit1_self operand
      a.y = x * (1.0f + gy);  // logit1_other
      a.z = y * (1.0f + gy);  // logit2_self
      a.w = y * (1.0f + gx);  // logit2_other
      *(float4*)&Al[rr][kk][0] = a;
    }
    __syncthreads();
    if (lane < 50) {
      const int cb = lane << 2;
#pragma unroll 4
      for (int kk = 0; kk < KC; ++kk) {
        const float4 av = *(const float4*)&Al[wid][kk][0];
        const float4 bv = *(const float4*)(wfc + (size_t)(k0 + kk) * C + cb);
        FMA16(av, bv);
      }
    }
  }
  if (lane < 50) {
    const int r = r0 + wid;
    const int cb = lane << 2;
    const float4 bb = *(const float4*)(bfc + cb);
#pragma unroll
    for (int v = 0; v < 4; ++v) {
      float4 o;
      o.x = sigm(acc[v][0] + bb.x);
      o.y = sigm(acc[v][1] + bb.y);
      o.z = sigm(acc[v][2] + bb.z);
      o.w = sigm(acc[v][3] + bb.w);
      *(float4*)(out + (size_t)v * NR * C + (size_t)r * C + cb) = o;
    }
  }
}

extern "C" void kernel_launch(void* const* d_in, const int* in_sizes, int n_in,
                              void* d_out, int out_size, void* d_ws, size_t ws_size,
                              hipStream_t stream) {
  const float* feats = (const float*)d_in[0];
  const int*   tgt   = (const int*)d_in[1];
  const float* w1    = (const float*)d_in[2];
  const float* b1    = (const float*)d_in[3];
  const float* w2    = (const float*)d_in[4];
  const float* b2    = (const float*)d_in[5];
  const float* wfc   = (const float*)d_in[6];
  const float* bfc   = (const float*)d_in[7];
  float* out = (float*)d_out;

  char* ws = (char*)d_ws;
  float* sq  = (float*)(ws);                 // 16 KB
  u64*   bi  = (u64*)(ws + 16384);           // 32 KB
  u64*   be  = (u64*)(ws + 49152);           // 32 KB
  int*   iy  = (int*)(ws + 81920);           // 32 KB
  float* hbuf = (float*)(ws + 131072);                              // 16 MB
  unsigned short* mbuf = (unsigned short*)(ws + 131072 + (size_t)NR * H * 4);  // 32 MB

  float* lab1 = out + (size_t)4 * NR * C;
  float* lab2 = lab1 + NR;

  k1_sumsq<<<N, 64, 0, stream>>>(feats, sq, bi, be);
  k2_dist<<<dim3(N / TS, N / TS), 256, 0, stream>>>(feats, tgt, sq, bi, be);
  k3_prep<<<NR / 256, 256, 0, stream>>>(tgt, bi, be, iy, lab1, lab2);
  k4_h<<<dim3(H / TS, NR / TS), 256, 0, stream>>>(feats, w1, b1, iy, hbuf);
  k5_m<<<dim3(D / TS, NR / TS), 256, 0, stream>>>(hbuf, w2, b2, mbuf);
  k6_logits<<<NR / 4, 256, 0, stream>>>(feats, mbuf, iy, wfc, bfc, out);
}

// Round 2
// 1037.161 us; speedup vs baseline: 2.4348x; 2.4348x over previous
//
#include <hip/hip_runtime.h>
#include <math.h>

#define N 4096
#define D 2048
#define H 512
#define C 200
#define NR 8192  // 2N
#define LDH 40   // padded LDS row stride in halves (80 B)

typedef unsigned long long u64;
typedef unsigned int u32;
typedef float f32x4 __attribute__((ext_vector_type(4)));
typedef _Float16 f16x8 __attribute__((ext_vector_type(8)));
typedef _Float16 f16x4 __attribute__((ext_vector_type(4)));

__device__ __forceinline__ float sigm(float z) { return 1.0f / (1.0f + expf(-z)); }
__device__ __forceinline__ float bf2f(unsigned short u) { return __uint_as_float(((u32)u) << 16); }
__device__ __forceinline__ unsigned short f2bf(float x) {
  u32 u = __float_as_uint(x);
  return (unsigned short)((u + 0x7fffu + ((u >> 16) & 1u)) >> 16);  // RNE
}

#define FMA16(av, bv) do { \
  acc[0][0] = fmaf(av.x, bv.x, acc[0][0]); \
  acc[0][1] = fmaf(av.x, bv.y, acc[0][1]); \
  acc[0][2] = fmaf(av.x, bv.z, acc[0][2]); \
  acc[0][3] = fmaf(av.x, bv.w, acc[0][3]); \
  acc[1][0] = fmaf(av.y, bv.x, acc[1][0]); \
  acc[1][1] = fmaf(av.y, bv.y, acc[1][1]); \
  acc[1][2] = fmaf(av.y, bv.z, acc[1][2]); \
  acc[1][3] = fmaf(av.y, bv.w, acc[1][3]); \
  acc[2][0] = fmaf(av.z, bv.x, acc[2][0]); \
  acc[2][1] = fmaf(av.z, bv.y, acc[2][1]); \
  acc[2][2] = fmaf(av.z, bv.z, acc[2][2]); \
  acc[2][3] = fmaf(av.z, bv.w, acc[2][3]); \
  acc[3][0] = fmaf(av.w, bv.x, acc[3][0]); \
  acc[3][1] = fmaf(av.w, bv.y, acc[3][1]); \
  acc[3][2] = fmaf(av.w, bv.z, acc[3][2]); \
  acc[3][3] = fmaf(av.w, bv.w, acc[3][3]); \
} while (0)

// ---------------- KC: split feats into f16 hi/lo ----------------
__global__ __launch_bounds__(256) void kc_split(const float* __restrict__ f,
                                                _Float16* __restrict__ hi,
                                                _Float16* __restrict__ lo) {
  const int idx = blockIdx.x * 256 + threadIdx.x;  // per 4 elements
  float4 v = ((const float4*)f)[idx];
  _Float16 h0 = (_Float16)v.x, h1 = (_Float16)v.y, h2 = (_Float16)v.z, h3 = (_Float16)v.w;
  f16x4 hv = {h0, h1, h2, h3};
  f16x4 lv = {(_Float16)(v.x - (float)h0), (_Float16)(v.y - (float)h1),
              (_Float16)(v.z - (float)h2), (_Float16)(v.w - (float)h3)};
  ((f16x4*)hi)[idx] = hv;
  ((f16x4*)lo)[idx] = lv;
}

// ---------------- KC: transpose fp32 [R][Cc] -> f16 [Cc][R] ----------------
__global__ void kc_T(const float* __restrict__ in, _Float16* __restrict__ out,
                     int R, int Cc) {
  __shared__ float t[32][33];
  const int c0 = blockIdx.x * 32, r0 = blockIdx.y * 32;
  for (int i = threadIdx.y; i < 32; i += 8)
    t[i][threadIdx.x] = in[(size_t)(r0 + i) * Cc + c0 + threadIdx.x];
  __syncthreads();
  for (int i = threadIdx.y; i < 32; i += 8)
    out[(size_t)(c0 + i) * R + r0 + threadIdx.x] = (_Float16)t[threadIdx.x][i];
}

// ---------------- K1: row sum of squares + init argmin buffers ----------------
__global__ __launch_bounds__(64) void k1_sumsq(const float* __restrict__ feats,
                                               float* __restrict__ sq,
                                               u64* __restrict__ bi, u64* __restrict__ be) {
  const int row = blockIdx.x;
  const float4* fp = (const float4*)(feats + (size_t)row * D);
  float s = 0.0f;
  for (int i = threadIdx.x; i < D / 4; i += 64) {
    float4 v = fp[i];
    s += v.x * v.x + v.y * v.y + v.z * v.z + v.w * v.w;
  }
  for (int off = 32; off > 0; off >>= 1) s += __shfl_down(s, off);
  if (threadIdx.x == 0) { sq[row] = s; bi[row] = ~0ull; be[row] = ~0ull; }
}

// ---------------- K2: Gram via f16x3 MFMA on upper triangle + fused argmin ----------------
__global__ __launch_bounds__(256, 2) void k2_dist(
    const _Float16* __restrict__ fhi, const _Float16* __restrict__ flo,
    const int* __restrict__ tgt, const float* __restrict__ sq,
    u64* __restrict__ bi, u64* __restrict__ be) {
  __shared__ __align__(16) _Float16 Ah[128 * LDH], Al[128 * LDH];
  __shared__ __align__(16) _Float16 Bh[128 * LDH], Bl[128 * LDH];
  __shared__ float sqi[128], sqj[128];
  __shared__ int ti[128], tj[128];
  __shared__ u64 Li[2][128], Lj[2][128];

  const int tid = threadIdx.x;
  const int b = blockIdx.x;
  int bj = (int)((sqrtf(8.0f * (float)b + 1.0f) - 1.0f) * 0.5f);
  while ((bj + 1) * (bj + 2) / 2 <= b) ++bj;
  while (bj * (bj + 1) / 2 > b) --bj;
  const int bib = b - bj * (bj + 1) / 2;
  const int i0 = bib * 128, j0 = bj * 128;
  const bool diag = (i0 == j0);

  if (tid < 128) { sqi[tid] = sq[i0 + tid]; ti[tid] = tgt[i0 + tid]; }
  else { const int t = tid - 128; sqj[t] = sq[j0 + t]; tj[t] = tgt[j0 + t]; }
  ((u64*)Li)[tid] = ~0ull;
  ((u64*)Lj)[tid] = ~0ull;

  const int l = tid & 63;
  const int w = tid >> 6;
  const int wr = w >> 1, wc = w & 1;
  const int fr = l & 15, fg = l >> 4;

  f32x4 acc[4][4] = {};

  for (int k0 = 0; k0 < D; k0 += 32) {
    __syncthreads();
#pragma unroll
    for (int it = 0; it < 2; ++it) {
      const int c = it * 256 + tid;
      const int row = c >> 2, xc = c & 3;
      const size_t gi = (size_t)(i0 + row) * D + k0 + xc * 8;
      const size_t gj = (size_t)(j0 + row) * D + k0 + xc * 8;
      const int la = row * LDH + xc * 8;
      *(uint4*)&Ah[la] = *(const uint4*)(fhi + gi);
      *(uint4*)&Al[la] = *(const uint4*)(flo + gi);
      *(uint4*)&Bh[la] = *(const uint4*)(fhi + gj);
      *(uint4*)&Bl[la] = *(const uint4*)(flo + gj);
    }
    __syncthreads();
    f16x8 ah[4], al[4], bh[4], bl[4];
#pragma unroll
    for (int m = 0; m < 4; ++m) {
      const int la = (wr * 64 + m * 16 + fr) * LDH + fg * 8;
      ah[m] = *(const f16x8*)&Ah[la];
      al[m] = *(const f16x8*)&Al[la];
    }
#pragma unroll
    for (int n = 0; n < 4; ++n) {
      const int lb = (wc * 64 + n * 16 + fr) * LDH + fg * 8;
      bh[n] = *(const f16x8*)&Bh[lb];
      bl[n] = *(const f16x8*)&Bl[lb];
    }
#pragma unroll
    for (int m = 0; m < 4; ++m)
#pragma unroll
      for (int n = 0; n < 4; ++n) {
        acc[m][n] = __builtin_amdgcn_mfma_f32_16x16x32_f16(ah[m], bh[n], acc[m][n], 0, 0, 0);
        acc[m][n] = __builtin_amdgcn_mfma_f32_16x16x32_f16(ah[m], bl[n], acc[m][n], 0, 0, 0);
        acc[m][n] = __builtin_amdgcn_mfma_f32_16x16x32_f16(al[m], bh[n], acc[m][n], 0, 0, 0);
      }
  }

  // ---- epilogue: row-i (this block's rows) argmin ----
#pragma unroll
  for (int m = 0; m < 4; ++m) {
#pragma unroll
    for (int reg = 0; reg < 4; ++reg) {
      const int row_l = wr * 64 + m * 16 + fg * 4 + reg;
      const float si = sqi[row_l];
      const int ci = ti[row_l];
      u64 ks = ~0ull, kd = ~0ull;
#pragma unroll
      for (int n = 0; n < 4; ++n) {
        const int col_l = wc * 64 + n * 16 + fr;
        const float d2 = si + sqj[col_l] - 2.0f * acc[m][n][reg];
        const u64 key = ((u64)__float_as_uint(d2) << 32) | (u32)(j0 + col_l);
        if (ci == tj[col_l]) {
          if (i0 + row_l != j0 + col_l) ks = key < ks ? key : ks;
        } else {
          kd = key < kd ? key : kd;
        }
      }
#pragma unroll
      for (int off = 1; off < 16; off <<= 1) {
        u64 o = __shfl_xor(ks, off); ks = o < ks ? o : ks;
        o = __shfl_xor(kd, off);     kd = o < kd ? o : kd;
      }
      if (fr == 0) {
        if (ks != ~0ull) atomicMin(&Li[0][row_l], ks);
        if (kd != ~0ull) atomicMin(&Li[1][row_l], kd);
      }
    }
  }
  // ---- epilogue: row-j (transposed) argmin, off-diagonal blocks only ----
  if (!diag) {
#pragma unroll
    for (int n = 0; n < 4; ++n) {
      const int col_l = wc * 64 + n * 16 + fr;
      const float sj = sqj[col_l];
      const int cj = tj[col_l];
      u64 ks = ~0ull, kd = ~0ull;
#pragma unroll
      for (int m = 0; m < 4; ++m)
#pragma unroll
        for (int reg = 0; reg < 4; ++reg) {
          const int row_l = wr * 64 + m * 16 + fg * 4 + reg;
          const float d2 = sqi[row_l] + sj - 2.0f * acc[m][n][reg];
          const u64 key = ((u64)__float_as_uint(d2) << 32) | (u32)(i0 + row_l);
          if (ti[row_l] == cj) ks = key < ks ? key : ks;
          else                 kd = key < kd ? key : kd;
        }
#pragma unroll
      for (int off = 16; off < 64; off <<= 1) {
        u64 o = __shfl_xor(ks, off); ks = o < ks ? o : ks;
        o = __shfl_xor(kd, off);     kd = o < kd ? o : kd;
      }
      if (fg == 0) {
        if (ks != ~0ull) atomicMin(&Lj[0][col_l], ks);
        if (kd != ~0ull) atomicMin(&Lj[1][col_l], kd);
      }
    }
  }
  __syncthreads();
  if (tid < 128) {
    u64 v = Li[0][tid]; if (v != ~0ull) atomicMin(&bi[i0 + tid], v);
    v = Li[1][tid];     if (v != ~0ull) atomicMin(&be[i0 + tid], v);
  } else if (!diag) {
    const int t = tid - 128;
    u64 v = Lj[0][t]; if (v != ~0ull) atomicMin(&bi[j0 + t], v);
    v = Lj[1][t];     if (v != ~0ull) atomicMin(&be[j0 + t], v);
  }
}

// ---------------- K3: extract pair indices + write label outputs ----------------
__global__ __launch_bounds__(256) void k3_prep(const int* __restrict__ tgt,
                                               const u64* __restrict__ bi,
                                               const u64* __restrict__ be,
                                               int* __restrict__ iy,
                                               float* __restrict__ lab1,
                                               float* __restrict__ lab2) {
  const int r = blockIdx.x * 256 + threadIdx.x;
  if (r >= NR) return;
  if (r < N) {
    iy[r] = (int)(bi[r] & 0xffffffffull);
    const float t = (float)tgt[r];
    lab1[r] = t; lab2[r] = t;
  } else {
    const int s = r - N;
    const int j = (int)(be[s] & 0xffffffffull);
    iy[r] = j;
    lab1[r] = (float)tgt[s];
    lab2[r] = (float)tgt[j];
  }
}

// ---------------- K4: h = [x,y] @ w1 + b1 via f16 MFMA ----------------
__global__ __launch_bounds__(256, 2) void k4_h(const _Float16* __restrict__ fhi,
                                               const _Float16* __restrict__ w1T,
                                               const float* __restrict__ b1,
                                               const int* __restrict__ iy,
                                               _Float16* __restrict__ hout) {
  __shared__ __align__(16) _Float16 As[128 * LDH], Bs[128 * LDH];
  __shared__ int iy_s[128];
  const int tid = threadIdx.x;
  const int n0 = blockIdx.x * 128, r0 = blockIdx.y * 128;
  if (tid < 128) iy_s[tid] = iy[r0 + tid];
  const int l = tid & 63, w = tid >> 6;
  const int wr = w >> 1, wc = w & 1, fr = l & 15, fg = l >> 4;
  f32x4 acc[4][4] = {};

  for (int k0 = 0; k0 < 2 * D; k0 += 32) {
    __syncthreads();
    const bool xh = (k0 < D);
    const int kb = xh ? k0 : k0 - D;
#pragma unroll
    for (int it = 0; it < 2; ++it) {
      const int c = it * 256 + tid;
      const int row = c >> 2, xc = c & 3;
      const int gr = xh ? ((r0 + row) & (N - 1)) : iy_s[row];
      const int la = row * LDH + xc * 8;
      *(uint4*)&As[la] = *(const uint4*)(fhi + (size_t)gr * D + kb + xc * 8);
      *(uint4*)&Bs[la] = *(const uint4*)(w1T + (size_t)(n0 + row) * (2 * D) + k0 + xc * 8);
    }
    __syncthreads();
    f16x8 a[4], bb[4];
#pragma unroll
    for (int m = 0; m < 4; ++m) a[m] = *(const f16x8*)&As[(wr * 64 + m * 16 + fr) * LDH + fg * 8];
#pragma unroll
    for (int n = 0; n < 4; ++n) bb[n] = *(const f16x8*)&Bs[(wc * 64 + n * 16 + fr) * LDH + fg * 8];
#pragma unroll
    for (int m = 0; m < 4; ++m)
#pragma unroll
      for (int n = 0; n < 4; ++n)
        acc[m][n] = __builtin_amdgcn_mfma_f32_16x16x32_f16(a[m], bb[n], acc[m][n], 0, 0, 0);
  }
#pragma unroll
  for (int n = 0; n < 4; ++n) {
    const int gcol = n0 + wc * 64 + n * 16 + fr;
    const float bias = b1[gcol];
#pragma unroll
    for (int m = 0; m < 4; ++m)
#pragma unroll
      for (int reg = 0; reg < 4; ++reg) {
        const int grow = r0 + wr * 64 + m * 16 + fg * 4 + reg;
        hout[(size_t)grow * H + gcol] = (_Float16)(acc[m][n][reg] + bias);
      }
  }
}

// ---------------- K5: m = h @ w2 + b2 via f16 MFMA (bf16 out) ----------------
__global__ __launch_bounds__(256, 2) void k5_m(const _Float16* __restrict__ hbuf,
                                               const _Float16* __restrict__ w2T,
                                               const float* __restrict__ b2,
                                               unsigned short* __restrict__ mbuf) {
  __shared__ __align__(16) _Float16 As[128 * LDH], Bs[128 * LDH];
  const int tid = threadIdx.x;
  const int n0 = blockIdx.x * 128, r0 = blockIdx.y * 128;
  const int l = tid & 63, w = tid >> 6;
  const int wr = w >> 1, wc = w & 1, fr = l & 15, fg = l >> 4;
  f32x4 acc[4][4] = {};

  for (int k0 = 0; k0 < H; k0 += 32) {
    __syncthreads();
#pragma unroll
    for (int it = 0; it < 2; ++it) {
      const int c = it * 256 + tid;
      const int row = c >> 2, xc = c & 3;
      const int la = row * LDH + xc * 8;
      *(uint4*)&As[la] = *(const uint4*)(hbuf + (size_t)(r0 + row) * H + k0 + xc * 8);
      *(uint4*)&Bs[la] = *(const uint4*)(w2T + (size_t)(n0 + row) * H + k0 + xc * 8);
    }
    __syncthreads();
    f16x8 a[4], bb[4];
#pragma unroll
    for (int m = 0; m < 4; ++m) a[m] = *(const f16x8*)&As[(wr * 64 + m * 16 + fr) * LDH + fg * 8];
#pragma unroll
    for (int n = 0; n < 4; ++n) bb[n] = *(const f16x8*)&Bs[(wc * 64 + n * 16 + fr) * LDH + fg * 8];
#pragma unroll
    for (int m = 0; m < 4; ++m)
#pragma unroll
      for (int n = 0; n < 4; ++n)
        acc[m][n] = __builtin_amdgcn_mfma_f32_16x16x32_f16(a[m], bb[n], acc[m][n], 0, 0, 0);
  }
#pragma unroll
  for (int n = 0; n < 4; ++n) {
    const int gcol = n0 + wc * 64 + n * 16 + fr;
    const float bias = b2[gcol];
#pragma unroll
    for (int m = 0; m < 4; ++m)
#pragma unroll
      for (int reg = 0; reg < 4; ++reg) {
        const int grow = r0 + wr * 64 + m * 16 + fg * 4 + reg;
        mbuf[(size_t)grow * D + gcol] = f2bf(acc[m][n][reg] + bias);
      }
  }
}

// ---------------- K6: fused gates + 4 logit GEMMs + sigmoid (fp32) ----------------
#define KC 1024
__global__ __launch_bounds__(256) void k6_logits(const float* __restrict__ feats,
                                                 const unsigned short* __restrict__ mbuf,
                                                 const int* __restrict__ iy,
                                                 const float* __restrict__ wfc,
                                                 const float* __restrict__ bfc,
                                                 float* __restrict__ out) {
  __shared__ float Al[4][KC][4];  // 64 KB
  const int tid = threadIdx.x;
  const int wid = tid >> 6;
  const int lane = tid & 63;
  const int r0 = blockIdx.x * 4;
  float acc[4][4] = {};

  for (int k0 = 0; k0 < D; k0 += KC) {
    __syncthreads();
#pragma unroll
    for (int rep = 0; rep < 16; ++rep) {
      const int idx = rep * 256 + tid;
      const int rr = idx >> 10;
      const int kk = idx & (KC - 1);
      const int rg = r0 + rr;
      const float x = feats[(size_t)(rg & (N - 1)) * D + k0 + kk];
      const float y = feats[(size_t)iy[rg] * D + k0 + kk];
      const float m = bf2f(mbuf[(size_t)rg * D + k0 + kk]);
      const float gx = sigm(m * x);
      const float gy = sigm(m * y);
      float4 a;
      a.x = x * (1.0f + gx);
      a.y = x * (1.0f + gy);
      a.z = y * (1.0f + gy);
      a.w = y * (1.0f + gx);
      *(float4*)&Al[rr][kk][0] = a;
    }
    __syncthreads();
    if (lane < 50) {
      const int cb = lane << 2;
#pragma unroll 4
      for (int kk = 0; kk < KC; ++kk) {
        const float4 av = *(const float4*)&Al[wid][kk][0];
        const float4 bv = *(const float4*)(wfc + (size_t)(k0 + kk) * C + cb);
        FMA16(av, bv);
      }
    }
  }
  if (lane < 50) {
    const int r = r0 + wid;
    const int cb = lane << 2;
    const float4 bb = *(const float4*)(bfc + cb);
#pragma unroll
    for (int v = 0; v < 4; ++v) {
      float4 o;
      o.x = sigm(acc[v][0] + bb.x);
      o.y = sigm(acc[v][1] + bb.y);
      o.z = sigm(acc[v][2] + bb.z);
      o.w = sigm(acc[v][3] + bb.w);
      *(float4*)(out + (size_t)v * NR * C + (size_t)r * C + cb) = o;
    }
  }
}

extern "C" void kernel_launch(void* const* d_in, const int* in_sizes, int n_in,
                              void* d_out, int out_size, void* d_ws, size_t ws_size,
                              hipStream_t stream) {
  const float* feats = (const float*)d_in[0];
  const int*   tgt   = (const int*)d_in[1];
  const float* w1    = (const float*)d_in[2];
  const float* b1    = (const float*)d_in[3];
  const float* w2    = (const float*)d_in[4];
  const float* b2    = (const float*)d_in[5];
  const float* wfc   = (const float*)d_in[6];
  const float* bfc   = (const float*)d_in[7];
  float* out = (float*)d_out;

  char* ws = (char*)d_ws;
  float* sq = (float*)(ws);                       // 16 KB
  u64*   bi = (u64*)(ws + 16384);                 // 32 KB
  u64*   be = (u64*)(ws + 49152);                 // 32 KB
  int*   iy = (int*)(ws + 81920);                 // 32 KB
  _Float16* fhi = (_Float16*)(ws + 131072);                  // 16 MB
  _Float16* flo = (_Float16*)(ws + 131072 + 16777216);       // 16 MB
  // mbuf (32 MB bf16) aliases fhi+flo — both dead before k5 writes it
  unsigned short* mbuf = (unsigned short*)(ws + 131072);
  _Float16* w1T = (_Float16*)(ws + 33685504);                // 4 MB
  _Float16* w2T = (_Float16*)(ws + 37879808);                // 2 MB
  _Float16* hbuf = (_Float16*)(ws + 39976960);               // 8 MB

  float* lab1 = out + (size_t)4 * NR * C;
  float* lab2 = lab1 + NR;

  kc_split<<<N * D / 1024, 256, 0, stream>>>(feats, fhi, flo);
  kc_T<<<dim3(512 / 32, 4096 / 32), dim3(32, 8), 0, stream>>>(w1, w1T, 4096, 512);
  kc_T<<<dim3(2048 / 32, 512 / 32), dim3(32, 8), 0, stream>>>(w2, w2T, 512, 2048);
  k1_sumsq<<<N, 64, 0, stream>>>(feats, sq, bi, be);
  k2_dist<<<528, 256, 0, stream>>>(fhi, flo, tgt, sq, bi, be);
  k3_prep<<<NR / 256, 256, 0, stream>>>(tgt, bi, be, iy, lab1, lab2);
  k4_h<<<dim3(H / 128, NR / 128), 256, 0, stream>>>(fhi, w1T, b1, iy, hbuf);
  k5_m<<<dim3(D / 128, NR / 128), 256, 0, stream>>>(hbuf, w2T, b2, mbuf);
  k6_logits<<<NR / 4, 256, 0, stream>>>(feats, mbuf, iy, wfc, bfc, out);
}

// Round 3
// 462.737 us; speedup vs baseline: 5.4573x; 2.2414x over previous
//
#include <hip/hip_runtime.h>
#include <math.h>

#define N 4096
#define D 2048
#define H 512
#define C 200
#define NR 8192  // 2N
#define LDH 40   // padded LDS row stride in halves (80 B)

typedef unsigned long long u64;
typedef unsigned int u32;
typedef float f32x4 __attribute__((ext_vector_type(4)));
typedef _Float16 f16x8 __attribute__((ext_vector_type(8)));
typedef _Float16 f16x4 __attribute__((ext_vector_type(4)));

__device__ __forceinline__ float sigm(float z) { return 1.0f / (1.0f + expf(-z)); }
__device__ __forceinline__ float bf2f(unsigned short u) { return __uint_as_float(((u32)u) << 16); }
__device__ __forceinline__ unsigned short f2bf(float x) {
  u32 u = __float_as_uint(x);
  return (unsigned short)((u + 0x7fffu + ((u >> 16) & 1u)) >> 16);  // RNE
}

// ---------------- KC: split feats into f16 hi/lo ----------------
__global__ __launch_bounds__(256) void kc_split(const float* __restrict__ f,
                                                _Float16* __restrict__ hi,
                                                _Float16* __restrict__ lo) {
  const int idx = blockIdx.x * 256 + threadIdx.x;  // per 4 elements
  float4 v = ((const float4*)f)[idx];
  _Float16 h0 = (_Float16)v.x, h1 = (_Float16)v.y, h2 = (_Float16)v.z, h3 = (_Float16)v.w;
  f16x4 hv = {h0, h1, h2, h3};
  f16x4 lv = {(_Float16)(v.x - (float)h0), (_Float16)(v.y - (float)h1),
              (_Float16)(v.z - (float)h2), (_Float16)(v.w - (float)h3)};
  ((f16x4*)hi)[idx] = hv;
  ((f16x4*)lo)[idx] = lv;
}

// ---------------- KC: transpose fp32 [R][Cc] -> f16 [Cc][R] ----------------
__global__ void kc_T(const float* __restrict__ in, _Float16* __restrict__ out,
                     int R, int Cc) {
  __shared__ float t[32][33];
  const int c0 = blockIdx.x * 32, r0 = blockIdx.y * 32;
  for (int i = threadIdx.y; i < 32; i += 8)
    t[i][threadIdx.x] = in[(size_t)(r0 + i) * Cc + c0 + threadIdx.x];
  __syncthreads();
  for (int i = threadIdx.y; i < 32; i += 8)
    out[(size_t)(c0 + i) * R + r0 + threadIdx.x] = (_Float16)t[threadIdx.x][i];
}

// ---------------- KC: wfc -> per-lane MFMA B-fragment layout (f16) ----------------
// wfcP[kc][nf][lane][j] = wfc[kc*32 + (lane>>4)*8 + j][nf*16 + (lane&15)], 0-padded
__global__ __launch_bounds__(64) void kc_wfc(const float* __restrict__ wfc,
                                             _Float16* __restrict__ wfcP) {
  const int kc = blockIdx.x, nf = blockIdx.y, l = threadIdx.x;
  const int n = nf * 16 + (l & 15);
  const int k = kc * 32 + (l >> 4) * 8;
  f16x8 v;
#pragma unroll
  for (int j = 0; j < 8; ++j)
    v[j] = (n < C) ? (_Float16)wfc[(size_t)(k + j) * C + n] : (_Float16)0.0f;
  *(f16x8*)(wfcP + ((size_t)(kc * 14 + nf) * 64 + l) * 8) = v;
}

// ---------------- K1: row sum of squares + init argmin buffers ----------------
__global__ __launch_bounds__(64) void k1_sumsq(const float* __restrict__ feats,
                                               float* __restrict__ sq,
                                               u64* __restrict__ bi, u64* __restrict__ be) {
  const int row = blockIdx.x;
  const float4* fp = (const float4*)(feats + (size_t)row * D);
  float s = 0.0f;
  for (int i = threadIdx.x; i < D / 4; i += 64) {
    float4 v = fp[i];
    s += v.x * v.x + v.y * v.y + v.z * v.z + v.w * v.w;
  }
  for (int off = 32; off > 0; off >>= 1) s += __shfl_down(s, off);
  if (threadIdx.x == 0) { sq[row] = s; bi[row] = ~0ull; be[row] = ~0ull; }
}

// ---------------- K2: Gram via f16x3 MFMA on upper triangle + fused argmin ----------------
__global__ __launch_bounds__(256, 2) void k2_dist(
    const _Float16* __restrict__ fhi, const _Float16* __restrict__ flo,
    const int* __restrict__ tgt, const float* __restrict__ sq,
    u64* __restrict__ bi, u64* __restrict__ be) {
  __shared__ __align__(16) _Float16 Ah[128 * LDH], Al[128 * LDH];
  __shared__ __align__(16) _Float16 Bh[128 * LDH], Bl[128 * LDH];
  __shared__ float sqi[128], sqj[128];
  __shared__ int ti[128], tj[128];
  __shared__ u64 Li[2][128], Lj[2][128];

  const int tid = threadIdx.x;
  const int b = blockIdx.x;
  int bj = (int)((sqrtf(8.0f * (float)b + 1.0f) - 1.0f) * 0.5f);
  while ((bj + 1) * (bj + 2) / 2 <= b) ++bj;
  while (bj * (bj + 1) / 2 > b) --bj;
  const int bib = b - bj * (bj + 1) / 2;
  const int i0 = bib * 128, j0 = bj * 128;
  const bool diag = (i0 == j0);

  if (tid < 128) { sqi[tid] = sq[i0 + tid]; ti[tid] = tgt[i0 + tid]; }
  else { const int t = tid - 128; sqj[t] = sq[j0 + t]; tj[t] = tgt[j0 + t]; }
  ((u64*)Li)[tid] = ~0ull;
  ((u64*)Lj)[tid] = ~0ull;

  const int l = tid & 63;
  const int w = tid >> 6;
  const int wr = w >> 1, wc = w & 1;
  const int fr = l & 15, fg = l >> 4;

  f32x4 acc[4][4] = {};

  for (int k0 = 0; k0 < D; k0 += 32) {
    __syncthreads();
#pragma unroll
    for (int it = 0; it < 2; ++it) {
      const int c = it * 256 + tid;
      const int row = c >> 2, xc = c & 3;
      const size_t gi = (size_t)(i0 + row) * D + k0 + xc * 8;
      const size_t gj = (size_t)(j0 + row) * D + k0 + xc * 8;
      const int la = row * LDH + xc * 8;
      *(uint4*)&Ah[la] = *(const uint4*)(fhi + gi);
      *(uint4*)&Al[la] = *(const uint4*)(flo + gi);
      *(uint4*)&Bh[la] = *(const uint4*)(fhi + gj);
      *(uint4*)&Bl[la] = *(const uint4*)(flo + gj);
    }
    __syncthreads();
    f16x8 ah[4], al[4], bh[4], bl[4];
#pragma unroll
    for (int m = 0; m < 4; ++m) {
      const int la = (wr * 64 + m * 16 + fr) * LDH + fg * 8;
      ah[m] = *(const f16x8*)&Ah[la];
      al[m] = *(const f16x8*)&Al[la];
    }
#pragma unroll
    for (int n = 0; n < 4; ++n) {
      const int lb = (wc * 64 + n * 16 + fr) * LDH + fg * 8;
      bh[n] = *(const f16x8*)&Bh[lb];
      bl[n] = *(const f16x8*)&Bl[lb];
    }
#pragma unroll
    for (int m = 0; m < 4; ++m)
#pragma unroll
      for (int n = 0; n < 4; ++n) {
        acc[m][n] = __builtin_amdgcn_mfma_f32_16x16x32_f16(ah[m], bh[n], acc[m][n], 0, 0, 0);
        acc[m][n] = __builtin_amdgcn_mfma_f32_16x16x32_f16(ah[m], bl[n], acc[m][n], 0, 0, 0);
        acc[m][n] = __builtin_amdgcn_mfma_f32_16x16x32_f16(al[m], bh[n], acc[m][n], 0, 0, 0);
      }
  }

  // ---- epilogue: row-i (this block's rows) argmin ----
#pragma unroll
  for (int m = 0; m < 4; ++m) {
#pragma unroll
    for (int reg = 0; reg < 4; ++reg) {
      const int row_l = wr * 64 + m * 16 + fg * 4 + reg;
      const float si = sqi[row_l];
      const int ci = ti[row_l];
      u64 ks = ~0ull, kd = ~0ull;
#pragma unroll
      for (int n = 0; n < 4; ++n) {
        const int col_l = wc * 64 + n * 16 + fr;
        const float d2 = si + sqj[col_l] - 2.0f * acc[m][n][reg];
        const u64 key = ((u64)__float_as_uint(d2) << 32) | (u32)(j0 + col_l);
        if (ci == tj[col_l]) {
          if (i0 + row_l != j0 + col_l) ks = key < ks ? key : ks;
        } else {
          kd = key < kd ? key : kd;
        }
      }
#pragma unroll
      for (int off = 1; off < 16; off <<= 1) {
        u64 o = __shfl_xor(ks, off); ks = o < ks ? o : ks;
        o = __shfl_xor(kd, off);     kd = o < kd ? o : kd;
      }
      if (fr == 0) {
        if (ks != ~0ull) atomicMin(&Li[0][row_l], ks);
        if (kd != ~0ull) atomicMin(&Li[1][row_l], kd);
      }
    }
  }
  // ---- epilogue: row-j (transposed) argmin, off-diagonal blocks only ----
  if (!diag) {
#pragma unroll
    for (int n = 0; n < 4; ++n) {
      const int col_l = wc * 64 + n * 16 + fr;
      const float sj = sqj[col_l];
      const int cj = tj[col_l];
      u64 ks = ~0ull, kd = ~0ull;
#pragma unroll
      for (int m = 0; m < 4; ++m)
#pragma unroll
        for (int reg = 0; reg < 4; ++reg) {
          const int row_l = wr * 64 + m * 16 + fg * 4 + reg;
          const float d2 = sqi[row_l] + sj - 2.0f * acc[m][n][reg];
          const u64 key = ((u64)__float_as_uint(d2) << 32) | (u32)(i0 + row_l);
          if (ti[row_l] == cj) ks = key < ks ? key : ks;
          else                 kd = key < kd ? key : kd;
        }
#pragma unroll
      for (int off = 16; off < 64; off <<= 1) {
        u64 o = __shfl_xor(ks, off); ks = o < ks ? o : ks;
        o = __shfl_xor(kd, off);     kd = o < kd ? o : kd;
      }
      if (fg == 0) {
        if (ks != ~0ull) atomicMin(&Lj[0][col_l], ks);
        if (kd != ~0ull) atomicMin(&Lj[1][col_l], kd);
      }
    }
  }
  __syncthreads();
  if (tid < 128) {
    u64 v = Li[0][tid]; if (v != ~0ull) atomicMin(&bi[i0 + tid], v);
    v = Li[1][tid];     if (v != ~0ull) atomicMin(&be[i0 + tid], v);
  } else if (!diag) {
    const int t = tid - 128;
    u64 v = Lj[0][t]; if (v != ~0ull) atomicMin(&bi[j0 + t], v);
    v = Lj[1][t];     if (v != ~0ull) atomicMin(&be[j0 + t], v);
  }
}

// ---------------- K3: extract pair indices + write label outputs ----------------
__global__ __launch_bounds__(256) void k3_prep(const int* __restrict__ tgt,
                                               const u64* __restrict__ bi,
                                               const u64* __restrict__ be,
                                               int* __restrict__ iy,
                                               float* __restrict__ lab1,
                                               float* __restrict__ lab2) {
  const int r = blockIdx.x * 256 + threadIdx.x;
  if (r >= NR) return;
  if (r < N) {
    iy[r] = (int)(bi[r] & 0xffffffffull);
    const float t = (float)tgt[r];
    lab1[r] = t; lab2[r] = t;
  } else {
    const int s = r - N;
    const int j = (int)(be[s] & 0xffffffffull);
    iy[r] = j;
    lab1[r] = (float)tgt[s];
    lab2[r] = (float)tgt[j];
  }
}

// ---------------- K4: h = [x,y] @ w1 + b1 via f16 MFMA ----------------
__global__ __launch_bounds__(256, 2) void k4_h(const _Float16* __restrict__ fhi,
                                               const _Float16* __restrict__ w1T,
                                               const float* __restrict__ b1,
                                               const int* __restrict__ iy,
                                               _Float16* __restrict__ hout) {
  __shared__ __align__(16) _Float16 As[128 * LDH], Bs[128 * LDH];
  __shared__ int iy_s[128];
  const int tid = threadIdx.x;
  const int n0 = blockIdx.x * 128, r0 = blockIdx.y * 128;
  if (tid < 128) iy_s[tid] = iy[r0 + tid];
  const int l = tid & 63, w = tid >> 6;
  const int wr = w >> 1, wc = w & 1, fr = l & 15, fg = l >> 4;
  f32x4 acc[4][4] = {};

  for (int k0 = 0; k0 < 2 * D; k0 += 32) {
    __syncthreads();
    const bool xh = (k0 < D);
    const int kb = xh ? k0 : k0 - D;
#pragma unroll
    for (int it = 0; it < 2; ++it) {
      const int c = it * 256 + tid;
      const int row = c >> 2, xc = c & 3;
      const int gr = xh ? ((r0 + row) & (N - 1)) : iy_s[row];
      const int la = row * LDH + xc * 8;
      *(uint4*)&As[la] = *(const uint4*)(fhi + (size_t)gr * D + kb + xc * 8);
      *(uint4*)&Bs[la] = *(const uint4*)(w1T + (size_t)(n0 + row) * (2 * D) + k0 + xc * 8);
    }
    __syncthreads();
    f16x8 a[4], bb[4];
#pragma unroll
    for (int m = 0; m < 4; ++m) a[m] = *(const f16x8*)&As[(wr * 64 + m * 16 + fr) * LDH + fg * 8];
#pragma unroll
    for (int n = 0; n < 4; ++n) bb[n] = *(const f16x8*)&Bs[(wc * 64 + n * 16 + fr) * LDH + fg * 8];
#pragma unroll
    for (int m = 0; m < 4; ++m)
#pragma unroll
      for (int n = 0; n < 4; ++n)
        acc[m][n] = __builtin_amdgcn_mfma_f32_16x16x32_f16(a[m], bb[n], acc[m][n], 0, 0, 0);
  }
#pragma unroll
  for (int n = 0; n < 4; ++n) {
    const int gcol = n0 + wc * 64 + n * 16 + fr;
    const float bias = b1[gcol];
#pragma unroll
    for (int m = 0; m < 4; ++m)
#pragma unroll
      for (int reg = 0; reg < 4; ++reg) {
        const int grow = r0 + wr * 64 + m * 16 + fg * 4 + reg;
        hout[(size_t)grow * H + gcol] = (_Float16)(acc[m][n][reg] + bias);
      }
  }
}

// ---------------- K5: m = h @ w2 + b2 via f16 MFMA (bf16 out) ----------------
__global__ __launch_bounds__(256, 2) void k5_m(const _Float16* __restrict__ hbuf,
                                               const _Float16* __restrict__ w2T,
                                               const float* __restrict__ b2,
                                               unsigned short* __restrict__ mbuf) {
  __shared__ __align__(16) _Float16 As[128 * LDH], Bs[128 * LDH];
  const int tid = threadIdx.x;
  const int n0 = blockIdx.x * 128, r0 = blockIdx.y * 128;
  const int l = tid & 63, w = tid >> 6;
  const int wr = w >> 1, wc = w & 1, fr = l & 15, fg = l >> 4;
  f32x4 acc[4][4] = {};

  for (int k0 = 0; k0 < H; k0 += 32) {
    __syncthreads();
#pragma unroll
    for (int it = 0; it < 2; ++it) {
      const int c = it * 256 + tid;
      const int row = c >> 2, xc = c & 3;
      const int la = row * LDH + xc * 8;
      *(uint4*)&As[la] = *(const uint4*)(hbuf + (size_t)(r0 + row) * H + k0 + xc * 8);
      *(uint4*)&Bs[la] = *(const uint4*)(w2T + (size_t)(n0 + row) * H + k0 + xc * 8);
    }
    __syncthreads();
    f16x8 a[4], bb[4];
#pragma unroll
    for (int m = 0; m < 4; ++m) a[m] = *(const f16x8*)&As[(wr * 64 + m * 16 + fr) * LDH + fg * 8];
#pragma unroll
    for (int n = 0; n < 4; ++n) bb[n] = *(const f16x8*)&Bs[(wc * 64 + n * 16 + fr) * LDH + fg * 8];
#pragma unroll
    for (int m = 0; m < 4; ++m)
#pragma unroll
      for (int n = 0; n < 4; ++n)
        acc[m][n] = __builtin_amdgcn_mfma_f32_16x16x32_f16(a[m], bb[n], acc[m][n], 0, 0, 0);
  }
#pragma unroll
  for (int n = 0; n < 4; ++n) {
    const int gcol = n0 + wc * 64 + n * 16 + fr;
    const float bias = b2[gcol];
#pragma unroll
    for (int m = 0; m < 4; ++m)
#pragma unroll
      for (int reg = 0; reg < 4; ++reg) {
        const int grow = r0 + wr * 64 + m * 16 + fg * 4 + reg;
        mbuf[(size_t)grow * D + gcol] = f2bf(acc[m][n][reg] + bias);
      }
  }
}

// ---------------- K6: fused gates + 4 logit GEMMs via f16 MFMA ----------------
// Block: 32 base rows x one N-half (7 frags of 16 cols). 4 waves = 4 variants.
__global__ __launch_bounds__(256, 2) void k6_logits(
    const float* __restrict__ feats, const unsigned short* __restrict__ mbuf,
    const int* __restrict__ iy, const _Float16* __restrict__ wfcP,
    const float* __restrict__ bfc, float* __restrict__ out) {
  __shared__ __align__(16) _Float16 As[128 * LDH];  // 10.2 KB
  __shared__ int iy_s[32];
  const int tid = threadIdx.x;
  const int nh = blockIdx.x;           // N-half: frags [nh*7, nh*7+7)
  const int r0 = blockIdx.y * 32;
  const int l = tid & 63, v = tid >> 6;  // wave = variant
  const int fr = l & 15, fg = l >> 4;
  if (tid < 32) iy_s[tid] = iy[r0 + tid];
  __syncthreads();
  const int rr = tid >> 3;             // base row 0..31
  const int kq = (tid & 7) << 2;       // k-quad 0,4,..28
  const int rg = r0 + rr;
  const float* xptr = feats + (size_t)(rg & (N - 1)) * D + kq;
  const float* yptr = feats + (size_t)iy_s[rr] * D + kq;
  const unsigned short* mptr = mbuf + (size_t)rg * D + kq;

  f32x4 acc[2][7] = {};
  float4 xv = *(const float4*)xptr;
  float4 yv = *(const float4*)yptr;
  ushort4 mv = *(const ushort4*)mptr;

  for (int k0 = 0; k0 < D; k0 += 32) {
    __syncthreads();
    {
      const float xs[4] = {xv.x, xv.y, xv.z, xv.w};
      const float ys[4] = {yv.x, yv.y, yv.z, yv.w};
      const unsigned short ms[4] = {mv.x, mv.y, mv.z, mv.w};
      f16x4 a0, a1, a2, a3;
#pragma unroll
      for (int j = 0; j < 4; ++j) {
        const float x = xs[j], y = ys[j], m = bf2f(ms[j]);
        const float gx = sigm(m * x), gy = sigm(m * y);
        a0[j] = (_Float16)(x * (1.0f + gx));
        a1[j] = (_Float16)(x * (1.0f + gy));
        a2[j] = (_Float16)(y * (1.0f + gy));
        a3[j] = (_Float16)(y * (1.0f + gx));
      }
      *(f16x4*)&As[(rr)      * LDH + kq] = a0;
      *(f16x4*)&As[(32 + rr) * LDH + kq] = a1;
      *(f16x4*)&As[(64 + rr) * LDH + kq] = a2;
      *(f16x4*)&As[(96 + rr) * LDH + kq] = a3;
    }
    if (k0 + 32 < D) {  // prefetch next K-chunk (hides under MFMA phase)
      xv = *(const float4*)(xptr + k0 + 32);
      yv = *(const float4*)(yptr + k0 + 32);
      mv = *(const ushort4*)(mptr + k0 + 32);
    }
    __syncthreads();
    const f16x8 a0 = *(const f16x8*)&As[(v * 32 + fr) * LDH + fg * 8];
    const f16x8 a1 = *(const f16x8*)&As[(v * 32 + 16 + fr) * LDH + fg * 8];
    const _Float16* bp = wfcP + ((size_t)(k0 >> 5) * 14 + nh * 7) * 512 + (size_t)l * 8;
#pragma unroll
    for (int nfl = 0; nfl < 7; ++nfl) {
      const f16x8 bf = *(const f16x8*)(bp + nfl * 512);
      acc[0][nfl] = __builtin_amdgcn_mfma_f32_16x16x32_f16(a0, bf, acc[0][nfl], 0, 0, 0);
      acc[1][nfl] = __builtin_amdgcn_mfma_f32_16x16x32_f16(a1, bf, acc[1][nfl], 0, 0, 0);
    }
  }
  float* outv = out + (size_t)v * NR * C;
#pragma unroll
  for (int nfl = 0; nfl < 7; ++nfl) {
    const int col = (nh * 7 + nfl) * 16 + fr;
    if (col < C) {
      const float bias = bfc[col];
#pragma unroll
      for (int mf = 0; mf < 2; ++mf) {
#pragma unroll
        for (int reg = 0; reg < 4; ++reg) {
          const int row = r0 + mf * 16 + fg * 4 + reg;
          outv[(size_t)row * C + col] = sigm(acc[mf][nfl][reg] + bias);
        }
      }
    }
  }
}

extern "C" void kernel_launch(void* const* d_in, const int* in_sizes, int n_in,
                              void* d_out, int out_size, void* d_ws, size_t ws_size,
                              hipStream_t stream) {
  const float* feats = (const float*)d_in[0];
  const int*   tgt   = (const int*)d_in[1];
  const float* w1    = (const float*)d_in[2];
  const float* b1    = (const float*)d_in[3];
  const float* w2    = (const float*)d_in[4];
  const float* b2    = (const float*)d_in[5];
  const float* wfc   = (const float*)d_in[6];
  const float* bfc   = (const float*)d_in[7];
  float* out = (float*)d_out;

  char* ws = (char*)d_ws;
  float* sq = (float*)(ws);                       // 16 KB
  u64*   bi = (u64*)(ws + 16384);                 // 32 KB
  u64*   be = (u64*)(ws + 49152);                 // 32 KB
  int*   iy = (int*)(ws + 81920);                 // 32 KB
  _Float16* fhi = (_Float16*)(ws + 131072);                  // 16 MB
  _Float16* flo = (_Float16*)(ws + 131072 + 16777216);       // 16 MB
  // mbuf (32 MB bf16) aliases fhi+flo — both dead before k5 writes it
  // (k6 reads feats fp32 directly, NOT fhi, so this stays legal)
  unsigned short* mbuf = (unsigned short*)(ws + 131072);
  _Float16* w1T = (_Float16*)(ws + 33685504);                // 4 MB
  _Float16* w2T = (_Float16*)(ws + 37879808);                // 2 MB
  _Float16* hbuf = (_Float16*)(ws + 39976960);               // 8 MB
  _Float16* wfcP = (_Float16*)(ws + 48365568);               // 0.9 MB

  float* lab1 = out + (size_t)4 * NR * C;
  float* lab2 = lab1 + NR;

  kc_split<<<N * D / 1024, 256, 0, stream>>>(feats, fhi, flo);
  kc_T<<<dim3(512 / 32, 4096 / 32), dim3(32, 8), 0, stream>>>(w1, w1T, 4096, 512);
  kc_T<<<dim3(2048 / 32, 512 / 32), dim3(32, 8), 0, stream>>>(w2, w2T, 512, 2048);
  kc_wfc<<<dim3(64, 14), 64, 0, stream>>>(wfc, wfcP);
  k1_sumsq<<<N, 64, 0, stream>>>(feats, sq, bi, be);
  k2_dist<<<528, 256, 0, stream>>>(fhi, flo, tgt, sq, bi, be);
  k3_prep<<<NR / 256, 256, 0, stream>>>(tgt, bi, be, iy, lab1, lab2);
  k4_h<<<dim3(H / 128, NR / 128), 256, 0, stream>>>(fhi, w1T, b1, iy, hbuf);
  k5_m<<<dim3(D / 128, NR / 128), 256, 0, stream>>>(hbuf, w2T, b2, mbuf);
  k6_logits<<<dim3(2, NR / 32), 256, 0, stream>>>(feats, mbuf, iy, wfcP, bfc, out);
}